// Round 1
// baseline (133.375 us; speedup 1.0000x reference)
//
#include <hip/hip_runtime.h>
#include <math.h>

// Capsule routing B=32, N=1024(j), D=256(k), NC=32(i), DC=64(d). Factored
// (no u_hat), MFMA 16x16x32 bf16:
//   delta[j,i] = U[b,j,:].w[:,i]    (k_pass phase D: A=U row-major, B=w hi/lo)
//   e = exp(logit), sef = sum_j e   (fp32 on reduced C-frags)
//   t[i,k] = sum_j e[i,j] U[j,k]    (k_pass phase T: A=e hi/lo, B=U fragments
//                                    read DIRECTLY from the row-major U tile)
//   s = tW_i; v = s*rsqrt(||s||^2+eps*sef^2); w = W_i v   (k_sv, fp32)
// Round-9: 64-j slices staged ONCE per pass (U read 1x not 2x, 3 barriers not
// 26, ~16 f2bf/thread not ~56). Delta K split 4-way across waves + LDS reduce.
// Round-10: U pre-converted to bf16 ONCE in k_init (Ubf, 16.8 MB ws). k_pass
// stages from Ubf with 2x v8s loads/thread: half the staging bytes, zero f2bf
// on the critical path, bit-identical numerics (same RNE conversion, done once).
// 77.3 KB LDS -> 2 blocks/CU. 6 plain launches, no atomics, no grid.sync.

typedef short v8s __attribute__((ext_vector_type(8)));
typedef short v4s __attribute__((ext_vector_type(4)));
typedef float v4f __attribute__((ext_vector_type(4)));

__device__ __forceinline__ unsigned short f2bf(float x) {
    unsigned u = __float_as_uint(x);
    u = u + 0x7fffu + ((u >> 16) & 1u);
    return (unsigned short)(u >> 16);
}
__device__ __forceinline__ float bf2f(unsigned short h) {
    return __uint_as_float(((unsigned)h) << 16);
}

// ---------------------------------------------------------------------------
// k_init: bid<512: colsum partials t0p[b][q][k] (iter-0 uniform softmax) AND
//         bf16 conversion of U into Ubf (read U once, emit both products);
//         bid>=512: transpose W (256x2048) -> WT (2048x256), 64x64 tiles.
__global__ __launch_bounds__(256) void k_init(const float* __restrict__ U,
                                              const float* __restrict__ W,
                                              float* __restrict__ t0p,
                                              float* __restrict__ WT,
                                              short* __restrict__ Ubf) {
    int bid = blockIdx.x, tid = threadIdx.x;
    if (bid < 512) {
        int b = bid >> 4, q = bid & 15;
        int row0 = (b << 10) + (q << 6);
        const float* Up = U + (row0 << 8) + tid;
        short* Ub = Ubf + (row0 << 8) + tid;
        float acc = 0.f;
        #pragma unroll 8
        for (int jl = 0; jl < 64; ++jl) {
            float x = Up[jl << 8];
            acc += x;
            Ub[jl << 8] = (short)f2bf(x);   // coalesced 512B/row bf16 store
        }
        t0p[(b << 12) + (q << 8) + tid] = acc * (1.0f / 1024.0f);
    } else {
        __shared__ float tile[64 * 65];
        int tix = bid - 512;                 // 0..127
        int k0 = (tix >> 5) << 6, c0 = (tix & 31) << 6;
        int cc = tid & 63, g4 = tid >> 6;
        #pragma unroll
        for (int r = 0; r < 16; ++r) {
            int kk = (g4 << 4) + r;
            tile[kk * 65 + cc] = W[(k0 + kk) * 2048 + c0 + cc];
        }
        __syncthreads();
        int kk = tid & 63;
        #pragma unroll
        for (int r = 0; r < 16; ++r) {
            int c = (g4 << 4) + r;
            WT[(c0 + c) * 256 + k0 + kk] = tile[kk * 65 + c];
        }
    }
}

// ---------------------------------------------------------------------------
// k_sv: per (b,iG): t[k] = sum of 16 partials; s = tW_i; v = squash(.,sef);
// w = W_i v -> wbt hi/lo (bf16). grid 1024, block 256.
__global__ __launch_bounds__(256) void k_sv(const float* __restrict__ t0p,
                                            const float* __restrict__ tpart,
                                            const float* __restrict__ sefpart,
                                            const float* __restrict__ W,
                                            const float* __restrict__ WT,
                                            short* __restrict__ wbt_h,
                                            short* __restrict__ wbt_l,
                                            float* __restrict__ out,
                                            int mode, int writeOut) {
    __shared__ float t_lds[256];
    __shared__ float spart[256];
    __shared__ __align__(16) float v_lds[64];
    __shared__ __align__(16) v4f spartw[256];
    __shared__ float sefv_s;
    int bid = blockIdx.x, tid = threadIdx.x;
    int b = bid >> 5, iG = bid & 31;
    int bg = (b << 1) | (iG >> 4), il = iG & 15;

    float acc = 0.f;
    if (mode == 0) {
        const float* tb = t0p + (b << 12) + tid;
        #pragma unroll
        for (int q = 0; q < 16; ++q) acc += tb[q << 8];
        if (tid == 0) sefv_s = 1.0f;
    } else {
        const float* tb = tpart + (((bg << 4) + il) << 8) + tid;
        #pragma unroll
        for (int p = 0; p < 16; ++p) acc += tb[p << 18];  // stride 64*16*256
        if (tid == 0) {
            float s = 0.f;
            #pragma unroll
            for (int p = 0; p < 16; ++p) s += sefpart[(p << 10) + (bg << 4) + il];
            sefv_s = s;
        }
    }
    t_lds[tid] = acc;
    __syncthreads();

    // s-phase: (d = tid&63, kq = tid>>6), coalesced 256B W reads
    int d = tid & 63, kq = tid >> 6;
    const float* Wc = W + ((kq << 6) * 2048) + (iG << 6) + d;
    float s = 0.f;
    #pragma unroll 4
    for (int kk = 0; kk < 64; ++kk)
        s += t_lds[(kq << 6) + kk] * Wc[kk * 2048];
    spart[tid] = s;
    __syncthreads();

    if (tid < 64) {
        float sv = spart[tid] + spart[tid + 64] + spart[tid + 128] + spart[tid + 192];
        float n2 = sv * sv;
        #pragma unroll
        for (int m = 1; m < 64; m <<= 1) n2 += __shfl_xor(n2, m, 64);
        float sf = sefv_s;
        float v = sv * rsqrtf(n2 + 1e-7f * sf * sf);
        v_lds[tid] = v;
        if (writeOut) out[(bid << 6) + tid] = v;
    }
    __syncthreads();
    if (writeOut) return;

    // w-phase: (k4 = tid&63, dq = tid>>6), WT gives coalesced 1KB/instr reads
    int k4 = tid & 63, dq = tid >> 6;
    const float4* WT4 = (const float4*)WT;
    v4f wp = {0.f, 0.f, 0.f, 0.f};
    #pragma unroll
    for (int dd = 0; dd < 16; ++dd) {
        float vv = v_lds[(dq << 4) + dd];
        float4 wt = WT4[((iG << 6) + (dq << 4) + dd) * 64 + k4];
        wp.x += vv * wt.x; wp.y += vv * wt.y; wp.z += vv * wt.z; wp.w += vv * wt.w;
    }
    spartw[(dq << 6) + k4] = wp;
    __syncthreads();
    if (tid < 64) {
        v4f w = spartw[tid] + spartw[64 + tid] + spartw[128 + tid] + spartw[192 + tid];
        float wv4[4] = {w.x, w.y, w.z, w.w};
        unsigned short wh[4], wl[4];
        #pragma unroll
        for (int e = 0; e < 4; ++e) {
            wh[e] = f2bf(wv4[e]);
            wl[e] = f2bf(wv4[e] - bf2f(wh[e]));
        }
        int base = (((bg << 4) + il) << 8) + (tid << 2);
        *(v4s*)&wbt_h[base] = (v4s){(short)wh[0], (short)wh[1], (short)wh[2], (short)wh[3]};
        *(v4s*)&wbt_l[base] = (v4s){(short)wl[0], (short)wl[1], (short)wl[2], (short)wl[3]};
    }
}

// ---------------------------------------------------------------------------
// k_pass v4: block = (b, p = 64-j slice, g2 = 16-capsule group), grid 1024x1024.
// Stage Ubf[64j][256k] bf16 ONCE (2x v8s/thread, no conversion); phase D
// (delta) splits K 4-ways over 16 waves (4 j-tiles x 4 K-quarters) + LDS
// reduce; phase T reads U B-fragments directly from the row-major tile
// (8x ds_read_u16). 3 barriers total.
__global__ __launch_bounds__(1024, 8) void k_pass(const short* __restrict__ Ubf,
                                                  const short* __restrict__ wbt_h,
                                                  const short* __restrict__ wbt_l,
                                                  float* __restrict__ bmatg,
                                                  float* __restrict__ tpart_out,
                                                  float* __restrict__ sefpart_out,
                                                  int addold) {
    __shared__ short s_U[64 * 268];      // 34,304 B [j][k] pad 12 (bank-spread)
    __shared__ short s_wh[16 * 264];     // 8,448
    __shared__ short s_wl[16 * 264];     // 8,448
    __shared__ short s_eh[16 * 72];      // 2,304  [i][j] pad 8
    __shared__ short s_el[16 * 72];      // 2,304
    __shared__ float s_red[16 * 320];    // 20,480 [kq*4+mt][rr*20+nn] (2-way banks)
    __shared__ float s_sefp[16 * 16];    // 1,024            total 77,312 B

    const int tid = threadIdx.x, wv = tid >> 6, lane = tid & 63;
    const int quad = lane >> 4, nn = lane & 15;
    const int blk = blockIdx.x;
    const int b = blk & 31, pg = blk >> 5;   // same-b blocks share XCD
    const int p = pg >> 1, g2 = pg & 1;
    const int bg = (b << 1) | g2;
    const int rowbase = (b << 10) + (p << 6);

    // reduce-phase lane mapping (also used for the bold prefetch)
    const int mt2 = wv & 3, jq = wv >> 2;
    const int rr = (jq << 2) + quad;
    const int jloc = (mt2 << 4) + rr;
    const int ga = (((bg << 10) + (p << 6) + jloc) << 4) + nn;  // bmat [bg][j][i]
    float bold = 0.f;
    if (addold) bold = bmatg[ga];

    // stage w hi/lo (waves 0-7)
    if (tid < 512) {
        int row = tid >> 5, seg = tid & 31;
        int gidx = (((bg << 4) + row) << 8) + (seg << 3);
        *(v8s*)&s_wh[row * 264 + (seg << 3)] = *(const v8s*)(wbt_h + gidx);
        *(v8s*)&s_wl[row * 264 + (seg << 3)] = *(const v8s*)(wbt_l + gidx);
    }
    // stage U once from Ubf (bf16): 2 sweeps of 32 rows x 32 x 16B, pure copy
    {
        const short* Ub = Ubf + (rowbase << 8);
        int col = tid & 31, row0 = tid >> 5;
        v8s u0 = *(const v8s*)(Ub + (row0 << 8) + (col << 3));
        v8s u1 = *(const v8s*)(Ub + ((row0 + 32) << 8) + (col << 3));
        *(v4s*)&s_U[row0 * 268 + (col << 3)]            = __builtin_shufflevector(u0, u0, 0, 1, 2, 3);
        *(v4s*)&s_U[row0 * 268 + (col << 3) + 4]        = __builtin_shufflevector(u0, u0, 4, 5, 6, 7);
        *(v4s*)&s_U[(row0 + 32) * 268 + (col << 3)]     = __builtin_shufflevector(u1, u1, 0, 1, 2, 3);
        *(v4s*)&s_U[(row0 + 32) * 268 + (col << 3) + 4] = __builtin_shufflevector(u1, u1, 4, 5, 6, 7);
    }
    __syncthreads();

    // ---- phase D: delta partials, wave = (mt = j-tile, kq = K-quarter) ----
    {
        const int mt = wv & 3, kq = wv >> 2;
        v4f dacc = {0.f, 0.f, 0.f, 0.f};
        #pragma unroll
        for (int c = 0; c < 2; ++c) {
            int kb = (kq << 6) + (c << 5) + (quad << 3);
            v8s a  = *(const v8s*)&s_U[((mt << 4) + nn) * 268 + kb];
            v8s bh = *(const v8s*)&s_wh[nn * 264 + kb];
            v8s bl = *(const v8s*)&s_wl[nn * 264 + kb];
            dacc = __builtin_amdgcn_mfma_f32_16x16x32_bf16(a, bh, dacc, 0, 0, 0);
            dacc = __builtin_amdgcn_mfma_f32_16x16x32_bf16(a, bl, dacc, 0, 0, 0);
        }
        #pragma unroll
        for (int r = 0; r < 4; ++r)
            s_red[wv * 320 + ((quad << 2) + r) * 20 + nn] = dacc[r];
    }
    __syncthreads();

    // ---- K-reduce + logits + exp + e hi/lo + sef partials ----
    {
        float val = bold;
        #pragma unroll
        for (int kq = 0; kq < 4; ++kq)
            val += s_red[((kq << 2) + mt2) * 320 + rr * 20 + nn];
        if (!addold) bmatg[ga] = val;
        float e = __expf(val);
        unsigned short eh = f2bf(e);
        s_eh[nn * 72 + jloc] = (short)eh;
        s_el[nn * 72 + jloc] = (short)f2bf(e - bf2f(eh));
        float se = e;
        se += __shfl_xor(se, 16, 64);
        se += __shfl_xor(se, 32, 64);
        if (lane < 16) s_sefp[(wv << 4) + lane] = se;
    }
    __syncthreads();

    // ---- phase T: wave = 16-k N-tile; A = e hi/lo, B = U direct fragments ----
    {
        v4f tacc = {0.f, 0.f, 0.f, 0.f};
        const int k0 = wv << 4;
        #pragma unroll
        for (int jc = 0; jc < 2; ++jc) {
            v8s aeh = *(const v8s*)&s_eh[nn * 72 + (jc << 5) + (quad << 3)];
            v8s ael = *(const v8s*)&s_el[nn * 72 + (jc << 5) + (quad << 3)];
            short bu[8];
            #pragma unroll
            for (int jj = 0; jj < 8; ++jj)
                bu[jj] = s_U[((jc << 5) + (quad << 3) + jj) * 268 + k0 + nn];
            v8s bf = (v8s){bu[0], bu[1], bu[2], bu[3], bu[4], bu[5], bu[6], bu[7]};
            tacc = __builtin_amdgcn_mfma_f32_16x16x32_bf16(aeh, bf, tacc, 0, 0, 0);
            tacc = __builtin_amdgcn_mfma_f32_16x16x32_bf16(ael, bf, tacc, 0, 0, 0);
        }
        // D: row = i = quad*4+r, col = k-local = nn
        #pragma unroll
        for (int r = 0; r < 4; ++r) {
            int i = (quad << 2) + r;
            tpart_out[(((((p << 6) + bg) << 4) + i) << 8) + k0 + nn] = tacc[r];
        }
    }
    if (tid < 16) {
        float ss = 0.f;
        #pragma unroll
        for (int w = 0; w < 16; ++w) ss += s_sefp[(w << 4) + tid];
        sefpart_out[(p << 10) + (bg << 4) + tid] = ss;
    }
}

// ---------------------------------------------------------------------------
extern "C" void kernel_launch(void* const* d_in, const int* in_sizes, int n_in,
                              void* d_out, int out_size, void* d_ws, size_t ws_size,
                              hipStream_t stream) {
    const float* U = (const float*)d_in[0];   // [32,1024,256]
    const float* W = (const float*)d_in[1];   // [256,2048]
    float* out = (float*)d_out;               // [32,32,64]
    float* ws = (float*)d_ws;

    // ws (float slots): ~24 MB fp32 + 1 MB wbt + 16.8 MB Ubf = ~41.5 MB
    float* t0p   = ws;                  // [32][16][256]      = 131,072
    float* WT    = t0p + 131072;        // [2048][256]        = 524,288
    float* bmatg = WT + 524288;         // [64][1024][16]     = 1,048,576
    float* tp    = bmatg + 1048576;     // [16][64][16][256]  = 4,194,304
    float* sef   = tp + 4194304;        // [16][64][16]       = 16,384
    short* wbt_h = (short*)(sef + 16384);   // [64][16][256] shorts
    short* wbt_l = wbt_h + 262144;
    short* Ubf   = wbt_l + 262144;      // [32][1024][256] bf16 = 16.8 MB

    k_init<<<640, 256, 0, stream>>>(U, W, t0p, WT, Ubf);
    k_sv<<<1024, 256, 0, stream>>>(t0p, nullptr, nullptr, W, WT,
                                   wbt_h, wbt_l, out, 0, 0);
    k_pass<<<1024, 1024, 0, stream>>>(Ubf, wbt_h, wbt_l, bmatg, tp, sef, 0);
    k_sv<<<1024, 256, 0, stream>>>(t0p, tp, sef, W, WT,
                                   wbt_h, wbt_l, out, 1, 0);
    k_pass<<<1024, 1024, 0, stream>>>(Ubf, wbt_h, wbt_l, bmatg, tp, sef, 1);
    k_sv<<<1024, 256, 0, stream>>>(t0p, tp, sef, W, WT,
                                   wbt_h, wbt_l, out, 1, 1);
}